// Round 1
// baseline (116.203 us; speedup 1.0000x reference)
//
#include <hip/hip_runtime.h>
#include <math.h>

#define N_SURF 40000
#define N_LIG  1024
#define HID    512
#define TDIM   64
#define E_MAX  131072
#define L5     5

// workspace float layout
#define WS_WP     0        // 512*3  : W_gcn[5] @ W_pos
#define WS_A3     1536     // 9      : W_surf @ Wp
#define WS_BSP    1545     // 3      : b_surf @ Wp
#define WS_BPOUT  1548     // 3      : b_gcn[5]@W_pos + b_pos
#define WS_AGG    1552     // 1024*3 : sum of surface_pos over in-edges
#define WS_CNT    4624     // 1024   : in-degree
#define WS_ZERO_BEGIN 1552
#define WS_ZERO_COUNT 4096

// ---- precompute Wp = W_gcn[5] @ W_pos (512x3), zero agg/cnt ----
__global__ void k_prep1(const float* __restrict__ Wgcn, const float* __restrict__ Wpos,
                        float* __restrict__ ws) {
    int lane = threadIdx.x & 63;
    int w    = threadIdx.x >> 6;
    int k    = blockIdx.x * 4 + w;                 // 128 blocks * 4 waves = 512 rows
    const float* Wg5 = Wgcn + (size_t)L5 * HID * HID + (size_t)k * HID;
    float a0 = 0.f, a1 = 0.f, a2 = 0.f;
    for (int j = lane; j < HID; j += 64) {         // coalesced row read
        float v = Wg5[j];
        a0 += v * Wpos[j * 3 + 0];
        a1 += v * Wpos[j * 3 + 1];
        a2 += v * Wpos[j * 3 + 2];
    }
    for (int m = 32; m; m >>= 1) {
        a0 += __shfl_xor(a0, m);
        a1 += __shfl_xor(a1, m);
        a2 += __shfl_xor(a2, m);
    }
    if (lane == 0) {
        ws[WS_WP + k * 3 + 0] = a0;
        ws[WS_WP + k * 3 + 1] = a1;
        ws[WS_WP + k * 3 + 2] = a2;
    }
    int idx = blockIdx.x * blockDim.x + threadIdx.x;   // 32768 threads total
    if (idx < WS_ZERO_COUNT) ws[WS_ZERO_BEGIN + idx] = 0.f;
}

// ---- tiny folds: A3 = W_surf@Wp, bsp = b_surf@Wp, bpout = b_gcn5@W_pos + b_pos ----
__global__ void k_prep2(const float* __restrict__ Wsurf, const float* __restrict__ bsurf,
                        const float* __restrict__ bgcn,  const float* __restrict__ Wpos,
                        const float* __restrict__ bpos,  float* __restrict__ ws) {
    int t = threadIdx.x;
    if (t < 9) {
        int a = t / 3, jp = t - a * 3;
        float acc = 0.f;
        for (int k = 0; k < HID; ++k) acc += Wsurf[a * HID + k] * ws[WS_WP + k * 3 + jp];
        ws[WS_A3 + t] = acc;
    } else if (t < 12) {
        int jp = t - 9;
        float acc = 0.f;
        for (int k = 0; k < HID; ++k) acc += bsurf[k] * ws[WS_WP + k * 3 + jp];
        ws[WS_BSP + jp] = acc;
    } else if (t < 15) {
        int jp = t - 12;
        float acc = bpos[jp];
        for (int j = 0; j < HID; ++j) acc += bgcn[L5 * HID + j] * Wpos[j * 3 + jp];
        ws[WS_BPOUT + jp] = acc;
    }
}

// ---- edge aggregation: agg_pos[dst] += surface_pos[src]; cnt[dst] += 1 ----
__global__ void k_edges(const int* __restrict__ ei, const float* __restrict__ spos,
                        float* __restrict__ ws) {
    int e = blockIdx.x * blockDim.x + threadIdx.x;
    if (e >= E_MAX) return;
    int s = ei[e];
    int d = ei[E_MAX + e];
    if (s < N_SURF && d >= N_SURF) {   // w = (~mask_lig[src]) & mask_lig[dst]
        int li = d - N_SURF;
        atomicAdd(&ws[WS_AGG + li * 3 + 0], spos[s * 3 + 0]);
        atomicAdd(&ws[WS_AGG + li * 3 + 1], spos[s * 3 + 1]);
        atomicAdd(&ws[WS_AGG + li * 3 + 2], spos[s * 3 + 2]);
        atomicAdd(&ws[WS_CNT + li], 1.0f);
    }
}

// ---- per-ligand: time MLP, gating, fold into 3-dim output. one wave per node ----
__global__ __launch_bounds__(256) void k_lig(
    const float* __restrict__ lpos,  const float* __restrict__ tarr,
    const float* __restrict__ Wt1,   const float* __restrict__ bt1,
    const float* __restrict__ Wt2,   const float* __restrict__ bt2,
    const float* __restrict__ Wlig,  const float* __restrict__ blig,
    const float* __restrict__ Wgate, const float* __restrict__ bgate,
    const float* __restrict__ Whb,
    const float* __restrict__ ws,    float* __restrict__ out)
{
    __shared__ float s_emb[4][64];
    __shared__ float s_h1[4][256];
    __shared__ float s_ht[4][64];
    int lane = threadIdx.x & 63;
    int w    = threadIdx.x >> 6;
    int i    = blockIdx.x * 4 + w;                 // 256 blocks * 4 waves = 1024 nodes

    float t = tarr[i];
    // sinusoidal embedding: freqs[h] = exp(-ln(1e4)/31 * h)
    {
        int h = lane & 31;
        const float coef = -0.29710775f;           // -ln(10000)/31 (f32)
        float ang = t * expf(coef * (float)h);
        s_emb[w][lane] = (lane < 32) ? sinf(ang) : cosf(ang);
    }
    __syncthreads();
    // h1 = gelu(emb @ Wt1 + bt1), exact gelu
    #pragma unroll
    for (int r = 0; r < 4; ++r) {
        int c = r * 64 + lane;
        float acc = bt1[c];
        for (int k = 0; k < 64; ++k) acc += s_emb[w][k] * Wt1[k * 256 + c];
        acc = 0.5f * acc * (1.f + erff(acc * 0.70710678f));
        s_h1[w][c] = acc;
    }
    __syncthreads();
    // h_time = h1 @ Wt2 + bt2
    {
        float acc = bt2[lane];
        for (int c = 0; c < 256; ++c) acc += s_h1[w][c] * Wt2[c * 64 + lane];
        s_ht[w][lane] = acc;
    }
    __syncthreads();

    float px = lpos[i * 3 + 0], py = lpos[i * 3 + 1], pz = lpos[i * 3 + 2];
    float a0 = 0.f, a1 = 0.f, a2 = 0.f;
    #pragma unroll
    for (int r = 0; r < 8; ++r) {
        int j = r * 64 + lane;
        float g = bgate[j], hb = 0.f;
        for (int k = 0; k < 64; ++k) {
            float ht = s_ht[w][k];
            g  += ht * Wgate[k * 512 + j];
            hb += ht * Whb[k * 512 + j];
        }
        float p  = blig[j] + px * Wlig[j] + py * Wlig[512 + j] + pz * Wlig[1024 + j];
        float hl = p * (1.f / (1.f + expf(-g))) + hb;   // h_lig[j]
        a0 += hl * ws[WS_WP + j * 3 + 0];
        a1 += hl * ws[WS_WP + j * 3 + 1];
        a2 += hl * ws[WS_WP + j * 3 + 2];
    }
    for (int m = 32; m; m >>= 1) {
        a0 += __shfl_xor(a0, m);
        a1 += __shfl_xor(a1, m);
        a2 += __shfl_xor(a2, m);
    }
    if (lane == 0) {
        float d  = ws[WS_CNT + i];
        float s1 = 1.f / sqrtf(1.f + d);
        float s2 = 1.f / (1.f + d);
        float c  = s1 * d;
        float ax = s1 * ws[WS_AGG + i * 3 + 0];
        float ay = s1 * ws[WS_AGG + i * 3 + 1];
        float az = s1 * ws[WS_AGG + i * 3 + 2];
        float acc[3] = {a0, a1, a2};
        #pragma unroll
        for (int jp = 0; jp < 3; ++jp) {
            out[i * 3 + jp] = ax * ws[WS_A3 + 0 + jp] +
                              ay * ws[WS_A3 + 3 + jp] +
                              az * ws[WS_A3 + 6 + jp] +
                              c  * ws[WS_BSP + jp]    +
                              s2 * acc[jp]            +
                              ws[WS_BPOUT + jp];
        }
    }
}

extern "C" void kernel_launch(void* const* d_in, const int* in_sizes, int n_in,
                              void* d_out, int out_size, void* d_ws, size_t ws_size,
                              hipStream_t stream) {
    const float* spos  = (const float*)d_in[0];
    const float* lpos  = (const float*)d_in[1];
    const float* tarr  = (const float*)d_in[2];
    const int*   ei    = (const int*)  d_in[3];
    // d_in[4], d_in[5]: batch indices — unused (batch structure is implicit in edges)
    const float* Wsurf = (const float*)d_in[6];
    const float* bsurf = (const float*)d_in[7];
    const float* Wt1   = (const float*)d_in[8];
    const float* bt1   = (const float*)d_in[9];
    const float* Wt2   = (const float*)d_in[10];
    const float* bt2   = (const float*)d_in[11];
    const float* Wlig  = (const float*)d_in[12];
    const float* blig  = (const float*)d_in[13];
    const float* Wgate = (const float*)d_in[14];
    const float* bgate = (const float*)d_in[15];
    const float* Whb   = (const float*)d_in[16];
    const float* Wgcn  = (const float*)d_in[17];
    const float* bgcn  = (const float*)d_in[18];
    const float* Wpos  = (const float*)d_in[19];
    const float* bpos  = (const float*)d_in[20];
    float* ws  = (float*)d_ws;
    float* out = (float*)d_out;

    hipLaunchKernelGGL(k_prep1, dim3(128), dim3(256), 0, stream, Wgcn, Wpos, ws);
    hipLaunchKernelGGL(k_prep2, dim3(1),   dim3(64),  0, stream, Wsurf, bsurf, bgcn, Wpos, bpos, ws);
    hipLaunchKernelGGL(k_edges, dim3(E_MAX / 256), dim3(256), 0, stream, ei, spos, ws);
    hipLaunchKernelGGL(k_lig,   dim3(N_LIG / 4),   dim3(256), 0, stream,
                       lpos, tarr, Wt1, bt1, Wt2, bt2, Wlig, blig, Wgate, bgate, Whb, ws, out);
}

// Round 2
// 106.526 us; speedup vs baseline: 1.0908x; 1.0908x over previous
//
#include <hip/hip_runtime.h>
#include <math.h>

#define N_SURF 40000
#define N_LIG  1024
#define HID    512
#define TDIM   64
#define E_MAX  131072
#define L5     5

// workspace float layout
#define WS_WP     0        // 512*3  : Wp = W_gcn[5] @ W_pos
#define WS_A3     1536     // 9      : W_surf @ Wp
#define WS_BSP    1545     // 3      : b_surf @ Wp
#define WS_BPOUT  1548     // 3      : b_gcn[5]@W_pos + b_pos
#define WS_WHBP   1552     // 64*3   : W_hbias @ Wp
#define WS_AGG    1744     // 1024*3 : sum of surface_pos over in-edges
#define WS_CNT    4816     // 1024   : in-degree
#define WS_ZERO_BEGIN 1744
#define WS_ZERO_COUNT 4096

// ---- precompute Wp = W_gcn[5] @ W_pos (512x3), zero agg/cnt ----
__global__ void k_prep1(const float* __restrict__ Wgcn, const float* __restrict__ Wpos,
                        float* __restrict__ ws) {
    int lane = threadIdx.x & 63;
    int w    = threadIdx.x >> 6;
    int k    = blockIdx.x * 4 + w;                 // 128 blocks * 4 waves = 512 rows
    const float* Wg5 = Wgcn + (size_t)L5 * HID * HID + (size_t)k * HID;
    float a0 = 0.f, a1 = 0.f, a2 = 0.f;
    for (int j = lane; j < HID; j += 64) {         // coalesced row read
        float v = Wg5[j];
        a0 += v * Wpos[j * 3 + 0];
        a1 += v * Wpos[j * 3 + 1];
        a2 += v * Wpos[j * 3 + 2];
    }
    for (int m = 32; m; m >>= 1) {
        a0 += __shfl_xor(a0, m);
        a1 += __shfl_xor(a1, m);
        a2 += __shfl_xor(a2, m);
    }
    if (lane == 0) {
        ws[WS_WP + k * 3 + 0] = a0;
        ws[WS_WP + k * 3 + 1] = a1;
        ws[WS_WP + k * 3 + 2] = a2;
    }
    int idx = blockIdx.x * blockDim.x + threadIdx.x;   // 32768 threads total
    if (idx < WS_ZERO_COUNT) ws[WS_ZERO_BEGIN + idx] = 0.f;
}

// ---- folds depending on Wp: A3, bsp, bpout, Whbp. 207 wave-level 512-dots ----
// outputs: o<9: A3  | o<12: bsp | o<15: bpout | o<207: Whbp[o-15]
__global__ __launch_bounds__(256) void k_prep2(
    const float* __restrict__ Wsurf, const float* __restrict__ bsurf,
    const float* __restrict__ bgcn,  const float* __restrict__ Wpos,
    const float* __restrict__ bpos,  const float* __restrict__ Whb,
    float* __restrict__ ws) {
    int lane = threadIdx.x & 63;
    int w    = threadIdx.x >> 6;
    for (int o = w; o < 207; o += 4) {
        float acc = 0.f;
        if (o < 9) {
            int a = o / 3, jp = o - a * 3;
            for (int k = lane; k < HID; k += 64)
                acc += Wsurf[a * HID + k] * ws[WS_WP + k * 3 + jp];
        } else if (o < 12) {
            int jp = o - 9;
            for (int k = lane; k < HID; k += 64)
                acc += bsurf[k] * ws[WS_WP + k * 3 + jp];
        } else if (o < 15) {
            int jp = o - 12;
            for (int j = lane; j < HID; j += 64)
                acc += bgcn[L5 * HID + j] * Wpos[j * 3 + jp];
        } else {
            int r = (o - 15) / 3, jp = (o - 15) % 3;
            for (int j = lane; j < HID; j += 64)
                acc += Whb[r * HID + j] * ws[WS_WP + j * 3 + jp];
        }
        for (int m = 32; m; m >>= 1) acc += __shfl_xor(acc, m);
        if (lane == 0) {
            if (o < 9)        ws[WS_A3 + o] = acc;
            else if (o < 12)  ws[WS_BSP + (o - 9)] = acc;
            else if (o < 15)  ws[WS_BPOUT + (o - 12)] = acc + bpos[o - 12];
            else              ws[WS_WHBP + (o - 15)] = acc;
        }
    }
}

// ---- edge aggregation: agg_pos[dst] += surface_pos[src]; cnt[dst] += 1 ----
__global__ void k_edges(const int* __restrict__ ei, const float* __restrict__ spos,
                        float* __restrict__ ws) {
    int e = blockIdx.x * blockDim.x + threadIdx.x;
    if (e >= E_MAX) return;
    int s = ei[e];
    int d = ei[E_MAX + e];
    if (s < N_SURF && d >= N_SURF) {   // w = (~mask_lig[src]) & mask_lig[dst]
        int li = d - N_SURF;
        atomicAdd(&ws[WS_AGG + li * 3 + 0], spos[s * 3 + 0]);
        atomicAdd(&ws[WS_AGG + li * 3 + 1], spos[s * 3 + 1]);
        atomicAdd(&ws[WS_AGG + li * 3 + 2], spos[s * 3 + 2]);
        atomicAdd(&ws[WS_CNT + li], 1.0f);
    }
}

// ---- per-ligand: one BLOCK (256 thr) per node. time MLP + gating + 3-dim fold ----
__global__ __launch_bounds__(256) void k_lig(
    const float* __restrict__ lpos,  const float* __restrict__ tarr,
    const float* __restrict__ Wt1,   const float* __restrict__ bt1,
    const float* __restrict__ Wt2,   const float* __restrict__ bt2,
    const float* __restrict__ Wlig,  const float* __restrict__ blig,
    const float* __restrict__ Wgate, const float* __restrict__ bgate,
    const float* __restrict__ ws,    float* __restrict__ out)
{
    __shared__ float s_emb[64];
    __shared__ float s_h1[256];
    __shared__ float s_ht[64];
    __shared__ float s_red[256];
    __shared__ float s_out[12];
    int t    = threadIdx.x;
    int lane = t & 63;
    int w    = t >> 6;
    int i    = blockIdx.x;

    float tt = tarr[i];
    if (t < 64) {
        const float coef = -0.29710775f;           // -ln(10000)/31
        float ang = tt * expf(coef * (float)(t & 31));
        s_emb[t] = (t < 32) ? sinf(ang) : cosf(ang);
    }
    __syncthreads();
    // h1 = gelu(emb @ Wt1 + bt1): one column per thread
    {
        float acc = bt1[t];
        #pragma unroll
        for (int k = 0; k < 64; ++k) acc += s_emb[k] * Wt1[k * 256 + t];
        s_h1[t] = 0.5f * acc * (1.f + erff(acc * 0.70710678f));
    }
    __syncthreads();
    // ht = h1 @ Wt2 + bt2: 4-way k-split, wave w covers k in [w*64, w*64+64)
    {
        int c0 = w * 64;
        float acc = 0.f;
        #pragma unroll
        for (int k = 0; k < 64; ++k) acc += s_h1[c0 + k] * Wt2[(c0 + k) * 64 + lane];
        s_red[t] = acc;
    }
    __syncthreads();
    if (t < 64) s_ht[t] = bt2[t] + s_red[t] + s_red[t + 64] + s_red[t + 128] + s_red[t + 192];
    __syncthreads();

    float px = lpos[i * 3 + 0], py = lpos[i * 3 + 1], pz = lpos[i * 3 + 2];
    float a0 = 0.f, a1 = 0.f, a2 = 0.f;
    #pragma unroll
    for (int r = 0; r < 2; ++r) {
        int j = r * 256 + t;
        float g = bgate[j];
        #pragma unroll
        for (int k = 0; k < 64; ++k) g += s_ht[k] * Wgate[k * 512 + j];
        float p  = blig[j] + px * Wlig[j] + py * Wlig[512 + j] + pz * Wlig[1024 + j];
        float hl = p * (1.f / (1.f + expf(-g)));   // gated term (hbias folded via Whbp)
        a0 += hl * ws[WS_WP + j * 3 + 0];
        a1 += hl * ws[WS_WP + j * 3 + 1];
        a2 += hl * ws[WS_WP + j * 3 + 2];
    }
    // + h_time @ Whbp  (64x3, precomputed)
    if (t < 64) {
        float ht = s_ht[t];
        a0 += ht * ws[WS_WHBP + t * 3 + 0];
        a1 += ht * ws[WS_WHBP + t * 3 + 1];
        a2 += ht * ws[WS_WHBP + t * 3 + 2];
    }
    for (int m = 32; m; m >>= 1) {
        a0 += __shfl_xor(a0, m);
        a1 += __shfl_xor(a1, m);
        a2 += __shfl_xor(a2, m);
    }
    if (lane == 0) { s_out[w * 3 + 0] = a0; s_out[w * 3 + 1] = a1; s_out[w * 3 + 2] = a2; }
    __syncthreads();
    if (t == 0) {
        float b0 = s_out[0] + s_out[3] + s_out[6] + s_out[9];
        float b1 = s_out[1] + s_out[4] + s_out[7] + s_out[10];
        float b2 = s_out[2] + s_out[5] + s_out[8] + s_out[11];
        float d  = ws[WS_CNT + i];
        float s1 = 1.f / sqrtf(1.f + d);
        float s2 = 1.f / (1.f + d);
        float c  = s1 * d;
        float ax = s1 * ws[WS_AGG + i * 3 + 0];
        float ay = s1 * ws[WS_AGG + i * 3 + 1];
        float az = s1 * ws[WS_AGG + i * 3 + 2];
        float acc[3] = {b0, b1, b2};
        #pragma unroll
        for (int jp = 0; jp < 3; ++jp) {
            out[i * 3 + jp] = ax * ws[WS_A3 + 0 + jp] +
                              ay * ws[WS_A3 + 3 + jp] +
                              az * ws[WS_A3 + 6 + jp] +
                              c  * ws[WS_BSP + jp]    +
                              s2 * acc[jp]            +
                              ws[WS_BPOUT + jp];
        }
    }
}

extern "C" void kernel_launch(void* const* d_in, const int* in_sizes, int n_in,
                              void* d_out, int out_size, void* d_ws, size_t ws_size,
                              hipStream_t stream) {
    const float* spos  = (const float*)d_in[0];
    const float* lpos  = (const float*)d_in[1];
    const float* tarr  = (const float*)d_in[2];
    const int*   ei    = (const int*)  d_in[3];
    const float* Wsurf = (const float*)d_in[6];
    const float* bsurf = (const float*)d_in[7];
    const float* Wt1   = (const float*)d_in[8];
    const float* bt1   = (const float*)d_in[9];
    const float* Wt2   = (const float*)d_in[10];
    const float* bt2   = (const float*)d_in[11];
    const float* Wlig  = (const float*)d_in[12];
    const float* blig  = (const float*)d_in[13];
    const float* Wgate = (const float*)d_in[14];
    const float* bgate = (const float*)d_in[15];
    const float* Whb   = (const float*)d_in[16];
    const float* Wgcn  = (const float*)d_in[17];
    const float* bgcn  = (const float*)d_in[18];
    const float* Wpos  = (const float*)d_in[19];
    const float* bpos  = (const float*)d_in[20];
    float* ws  = (float*)d_ws;
    float* out = (float*)d_out;

    hipLaunchKernelGGL(k_prep1, dim3(128), dim3(256), 0, stream, Wgcn, Wpos, ws);
    hipLaunchKernelGGL(k_prep2, dim3(1),   dim3(256), 0, stream,
                       Wsurf, bsurf, bgcn, Wpos, bpos, Whb, ws);
    hipLaunchKernelGGL(k_edges, dim3(E_MAX / 256), dim3(256), 0, stream, ei, spos, ws);
    hipLaunchKernelGGL(k_lig,   dim3(N_LIG),       dim3(256), 0, stream,
                       lpos, tarr, Wt1, bt1, Wt2, bt2, Wlig, blig, Wgate, bgate, ws, out);
}

// Round 3
// 40.630 us; speedup vs baseline: 2.8600x; 2.6219x over previous
//
#include <hip/hip_runtime.h>
#include <math.h>

#define N_SURF 40000
#define N_LIG  1024
#define HID    512
#define TDIM   64
#define E_MAX  131072
#define L5     5

// workspace float layout
#define WS_WP     0        // 512*3  : Wp = W_gcn[5] @ W_pos
#define WS_A3     1536     // 9      : W_surf @ Wp
#define WS_BSP    1545     // 3      : b_surf @ Wp
#define WS_BPOUT  1548     // 3      : b_gcn[5]@W_pos + b_pos
#define WS_WHBP   1552     // 64*3   : W_hbias @ Wp
#define WS_AGG    1744     // 1024*3 : sum of surface_pos over in-edges
#define WS_CNT    4816     // 1024   : in-degree
#define WS_ZERO_BEGIN 1744
#define WS_ZERO_COUNT 4096

// ---- precompute Wp = W_gcn[5] @ W_pos (512x3), zero agg/cnt ----
__global__ void k_prep1(const float* __restrict__ Wgcn, const float* __restrict__ Wpos,
                        float* __restrict__ ws) {
    int lane = threadIdx.x & 63;
    int w    = threadIdx.x >> 6;
    int k    = blockIdx.x * 4 + w;                 // 128 blocks * 4 waves = 512 rows
    const float* Wg5 = Wgcn + (size_t)L5 * HID * HID + (size_t)k * HID;
    float a0 = 0.f, a1 = 0.f, a2 = 0.f;
    for (int j = lane; j < HID; j += 64) {         // coalesced row read
        float v = Wg5[j];
        a0 += v * Wpos[j * 3 + 0];
        a1 += v * Wpos[j * 3 + 1];
        a2 += v * Wpos[j * 3 + 2];
    }
    for (int m = 32; m; m >>= 1) {
        a0 += __shfl_xor(a0, m);
        a1 += __shfl_xor(a1, m);
        a2 += __shfl_xor(a2, m);
    }
    if (lane == 0) {
        ws[WS_WP + k * 3 + 0] = a0;
        ws[WS_WP + k * 3 + 1] = a1;
        ws[WS_WP + k * 3 + 2] = a2;
    }
    int idx = blockIdx.x * blockDim.x + threadIdx.x;   // 32768 threads total
    if (idx < WS_ZERO_COUNT) ws[WS_ZERO_BEGIN + idx] = 0.f;
}

// ---- folds depending on Wp: A3, bsp, bpout, Whbp. one WAVE per output ----
// outputs: o<9: A3  | o<12: bsp | o<15: bpout | o<207: Whbp[o-15]
__global__ __launch_bounds__(256) void k_prep2(
    const float* __restrict__ Wsurf, const float* __restrict__ bsurf,
    const float* __restrict__ bgcn,  const float* __restrict__ Wpos,
    const float* __restrict__ bpos,  const float* __restrict__ Whb,
    float* __restrict__ ws) {
    int lane = threadIdx.x & 63;
    int w    = threadIdx.x >> 6;
    int o    = blockIdx.x * 4 + w;                 // 52 blocks * 4 waves >= 207 outputs
    if (o >= 207) return;
    float acc = 0.f;
    if (o < 9) {
        int a = o / 3, jp = o - a * 3;
        for (int k = lane; k < HID; k += 64)
            acc += Wsurf[a * HID + k] * ws[WS_WP + k * 3 + jp];
    } else if (o < 12) {
        int jp = o - 9;
        for (int k = lane; k < HID; k += 64)
            acc += bsurf[k] * ws[WS_WP + k * 3 + jp];
    } else if (o < 15) {
        int jp = o - 12;
        for (int j = lane; j < HID; j += 64)
            acc += bgcn[L5 * HID + j] * Wpos[j * 3 + jp];
    } else {
        int r = (o - 15) / 3, jp = (o - 15) % 3;
        for (int j = lane; j < HID; j += 64)
            acc += Whb[r * HID + j] * ws[WS_WP + j * 3 + jp];
    }
    for (int m = 32; m; m >>= 1) acc += __shfl_xor(acc, m);
    if (lane == 0) {
        if (o < 9)        ws[WS_A3 + o] = acc;
        else if (o < 12)  ws[WS_BSP + (o - 9)] = acc;
        else if (o < 15)  ws[WS_BPOUT + (o - 12)] = acc + bpos[o - 12];
        else              ws[WS_WHBP + (o - 15)] = acc;
    }
}

// ---- edge aggregation: agg_pos[dst] += surface_pos[src]; cnt[dst] += 1 ----
__global__ void k_edges(const int* __restrict__ ei, const float* __restrict__ spos,
                        float* __restrict__ ws) {
    int e = blockIdx.x * blockDim.x + threadIdx.x;
    if (e >= E_MAX) return;
    int s = ei[e];
    int d = ei[E_MAX + e];
    if (s < N_SURF && d >= N_SURF) {   // w = (~mask_lig[src]) & mask_lig[dst]
        int li = d - N_SURF;
        atomicAdd(&ws[WS_AGG + li * 3 + 0], spos[s * 3 + 0]);
        atomicAdd(&ws[WS_AGG + li * 3 + 1], spos[s * 3 + 1]);
        atomicAdd(&ws[WS_AGG + li * 3 + 2], spos[s * 3 + 2]);
        atomicAdd(&ws[WS_CNT + li], 1.0f);
    }
}

// ---- per-ligand: one BLOCK (256 thr) per node. time MLP + gating + 3-dim fold ----
__global__ __launch_bounds__(256) void k_lig(
    const float* __restrict__ lpos,  const float* __restrict__ tarr,
    const float* __restrict__ Wt1,   const float* __restrict__ bt1,
    const float* __restrict__ Wt2,   const float* __restrict__ bt2,
    const float* __restrict__ Wlig,  const float* __restrict__ blig,
    const float* __restrict__ Wgate, const float* __restrict__ bgate,
    const float* __restrict__ ws,    float* __restrict__ out)
{
    __shared__ float s_emb[64];
    __shared__ float s_h1[256];
    __shared__ float s_ht[64];
    __shared__ float s_red[256];
    __shared__ float s_out[12];
    int t    = threadIdx.x;
    int lane = t & 63;
    int w    = t >> 6;
    int i    = blockIdx.x;

    float tt = tarr[i];
    if (t < 64) {
        const float coef = -0.29710775f;           // -ln(10000)/31
        float ang = tt * expf(coef * (float)(t & 31));
        s_emb[t] = (t < 32) ? sinf(ang) : cosf(ang);
    }
    __syncthreads();
    // h1 = gelu(emb @ Wt1 + bt1): one column per thread
    {
        float acc = bt1[t];
        #pragma unroll
        for (int k = 0; k < 64; ++k) acc += s_emb[k] * Wt1[k * 256 + t];
        s_h1[t] = 0.5f * acc * (1.f + erff(acc * 0.70710678f));
    }
    __syncthreads();
    // ht = h1 @ Wt2 + bt2: 4-way k-split, wave w covers k in [w*64, w*64+64)
    {
        int c0 = w * 64;
        float acc = 0.f;
        #pragma unroll
        for (int k = 0; k < 64; ++k) acc += s_h1[c0 + k] * Wt2[(c0 + k) * 64 + lane];
        s_red[t] = acc;
    }
    __syncthreads();
    if (t < 64) s_ht[t] = bt2[t] + s_red[t] + s_red[t + 64] + s_red[t + 128] + s_red[t + 192];
    __syncthreads();

    float px = lpos[i * 3 + 0], py = lpos[i * 3 + 1], pz = lpos[i * 3 + 2];
    float a0 = 0.f, a1 = 0.f, a2 = 0.f;
    #pragma unroll
    for (int r = 0; r < 2; ++r) {
        int j = r * 256 + t;
        float g = bgate[j];
        #pragma unroll
        for (int k = 0; k < 64; ++k) g += s_ht[k] * Wgate[k * 512 + j];
        float p  = blig[j] + px * Wlig[j] + py * Wlig[512 + j] + pz * Wlig[1024 + j];
        float hl = p * (1.f / (1.f + expf(-g)));   // gated term (hbias folded via Whbp)
        a0 += hl * ws[WS_WP + j * 3 + 0];
        a1 += hl * ws[WS_WP + j * 3 + 1];
        a2 += hl * ws[WS_WP + j * 3 + 2];
    }
    // + h_time @ Whbp  (64x3, precomputed)
    if (t < 64) {
        float ht = s_ht[t];
        a0 += ht * ws[WS_WHBP + t * 3 + 0];
        a1 += ht * ws[WS_WHBP + t * 3 + 1];
        a2 += ht * ws[WS_WHBP + t * 3 + 2];
    }
    for (int m = 32; m; m >>= 1) {
        a0 += __shfl_xor(a0, m);
        a1 += __shfl_xor(a1, m);
        a2 += __shfl_xor(a2, m);
    }
    if (lane == 0) { s_out[w * 3 + 0] = a0; s_out[w * 3 + 1] = a1; s_out[w * 3 + 2] = a2; }
    __syncthreads();
    if (t == 0) {
        float b0 = s_out[0] + s_out[3] + s_out[6] + s_out[9];
        float b1 = s_out[1] + s_out[4] + s_out[7] + s_out[10];
        float b2 = s_out[2] + s_out[5] + s_out[8] + s_out[11];
        float d  = ws[WS_CNT + i];
        float s1 = 1.f / sqrtf(1.f + d);
        float s2 = 1.f / (1.f + d);
        float c  = s1 * d;
        float ax = s1 * ws[WS_AGG + i * 3 + 0];
        float ay = s1 * ws[WS_AGG + i * 3 + 1];
        float az = s1 * ws[WS_AGG + i * 3 + 2];
        float acc[3] = {b0, b1, b2};
        #pragma unroll
        for (int jp = 0; jp < 3; ++jp) {
            out[i * 3 + jp] = ax * ws[WS_A3 + 0 + jp] +
                              ay * ws[WS_A3 + 3 + jp] +
                              az * ws[WS_A3 + 6 + jp] +
                              c  * ws[WS_BSP + jp]    +
                              s2 * acc[jp]            +
                              ws[WS_BPOUT + jp];
        }
    }
}

extern "C" void kernel_launch(void* const* d_in, const int* in_sizes, int n_in,
                              void* d_out, int out_size, void* d_ws, size_t ws_size,
                              hipStream_t stream) {
    const float* spos  = (const float*)d_in[0];
    const float* lpos  = (const float*)d_in[1];
    const float* tarr  = (const float*)d_in[2];
    const int*   ei    = (const int*)  d_in[3];
    const float* Wsurf = (const float*)d_in[6];
    const float* bsurf = (const float*)d_in[7];
    const float* Wt1   = (const float*)d_in[8];
    const float* bt1   = (const float*)d_in[9];
    const float* Wt2   = (const float*)d_in[10];
    const float* bt2   = (const float*)d_in[11];
    const float* Wlig  = (const float*)d_in[12];
    const float* blig  = (const float*)d_in[13];
    const float* Wgate = (const float*)d_in[14];
    const float* bgate = (const float*)d_in[15];
    const float* Whb   = (const float*)d_in[16];
    const float* Wgcn  = (const float*)d_in[17];
    const float* bgcn  = (const float*)d_in[18];
    const float* Wpos  = (const float*)d_in[19];
    const float* bpos  = (const float*)d_in[20];
    float* ws  = (float*)d_ws;
    float* out = (float*)d_out;

    hipLaunchKernelGGL(k_prep1, dim3(128), dim3(256), 0, stream, Wgcn, Wpos, ws);
    hipLaunchKernelGGL(k_prep2, dim3(52),  dim3(256), 0, stream,
                       Wsurf, bsurf, bgcn, Wpos, bpos, Whb, ws);
    hipLaunchKernelGGL(k_edges, dim3(E_MAX / 256), dim3(256), 0, stream, ei, spos, ws);
    hipLaunchKernelGGL(k_lig,   dim3(N_LIG),       dim3(256), 0, stream,
                       lpos, tarr, Wt1, bt1, Wt2, bt2, Wlig, blig, Wgate, bgate, ws, out);
}

// Round 4
// 37.701 us; speedup vs baseline: 3.0823x; 1.0777x over previous
//
#include <hip/hip_runtime.h>
#include <math.h>

#define N_SURF 40000
#define N_LIG  1024
#define HID    512
#define TDIM   64
#define E_MAX  131072
#define L5     5

// workspace float layout
#define WS_WP     0        // 512*3  : Wp = W_gcn[5] @ W_pos
#define WS_A3     1536     // 9      : W_surf @ Wp
#define WS_BSP    1545     // 3      : b_surf @ Wp
#define WS_BPOUT  1548     // 3      : b_gcn[5]@W_pos + b_pos
#define WS_WHBP   1552     // 64*3   : W_hbias @ Wp
#define WS_AGG    1744     // 1024*3 : sum of surface_pos over in-edges
#define WS_CNT    4816     // 1024   : in-degree
#define WS_ZERO_BEGIN 1744
#define WS_ZERO_COUNT 4096

// ---- precompute Wp = W_gcn[5] @ W_pos (512x3), zero agg/cnt ----
__global__ void k_prep1(const float* __restrict__ Wgcn, const float* __restrict__ Wpos,
                        float* __restrict__ ws) {
    int lane = threadIdx.x & 63;
    int w    = threadIdx.x >> 6;
    int k    = blockIdx.x * 4 + w;                 // 128 blocks * 4 waves = 512 rows
    const float* Wg5 = Wgcn + (size_t)L5 * HID * HID + (size_t)k * HID;
    float a0 = 0.f, a1 = 0.f, a2 = 0.f;
    for (int j = lane; j < HID; j += 64) {         // coalesced row read
        float v = Wg5[j];
        a0 += v * Wpos[j * 3 + 0];
        a1 += v * Wpos[j * 3 + 1];
        a2 += v * Wpos[j * 3 + 2];
    }
    for (int m = 32; m; m >>= 1) {
        a0 += __shfl_xor(a0, m);
        a1 += __shfl_xor(a1, m);
        a2 += __shfl_xor(a2, m);
    }
    if (lane == 0) {
        ws[WS_WP + k * 3 + 0] = a0;
        ws[WS_WP + k * 3 + 1] = a1;
        ws[WS_WP + k * 3 + 2] = a2;
    }
    int idx = blockIdx.x * blockDim.x + threadIdx.x;   // 32768 threads total
    if (idx < WS_ZERO_COUNT) ws[WS_ZERO_BEGIN + idx] = 0.f;
}

// ---- merged: blocks 0..51 = Wp-dependent folds; blocks 52..563 = edge scatter ----
// fold outputs: o<9: A3 | o<12: bsp | o<15: bpout | o<207: Whbp[o-15]
__global__ __launch_bounds__(256) void k_mid(
    const float* __restrict__ Wsurf, const float* __restrict__ bsurf,
    const float* __restrict__ bgcn,  const float* __restrict__ Wpos,
    const float* __restrict__ bpos,  const float* __restrict__ Whb,
    const int*   __restrict__ ei,    const float* __restrict__ spos,
    float* __restrict__ ws) {
    if (blockIdx.x < 52) {
        int lane = threadIdx.x & 63;
        int w    = threadIdx.x >> 6;
        int o    = blockIdx.x * 4 + w;             // 52*4 >= 207 outputs, one wave each
        if (o >= 207) return;
        float acc = 0.f;
        if (o < 9) {
            int a = o / 3, jp = o - a * 3;
            for (int k = lane; k < HID; k += 64)
                acc += Wsurf[a * HID + k] * ws[WS_WP + k * 3 + jp];
        } else if (o < 12) {
            int jp = o - 9;
            for (int k = lane; k < HID; k += 64)
                acc += bsurf[k] * ws[WS_WP + k * 3 + jp];
        } else if (o < 15) {
            int jp = o - 12;
            for (int j = lane; j < HID; j += 64)
                acc += bgcn[L5 * HID + j] * Wpos[j * 3 + jp];
        } else {
            int r = (o - 15) / 3, jp = (o - 15) % 3;
            for (int j = lane; j < HID; j += 64)
                acc += Whb[r * HID + j] * ws[WS_WP + j * 3 + jp];
        }
        for (int m = 32; m; m >>= 1) acc += __shfl_xor(acc, m);
        if (lane == 0) {
            if (o < 9)        ws[WS_A3 + o] = acc;
            else if (o < 12)  ws[WS_BSP + (o - 9)] = acc;
            else if (o < 15)  ws[WS_BPOUT + (o - 12)] = acc + bpos[o - 12];
            else              ws[WS_WHBP + (o - 15)] = acc;
        }
    } else {
        int e = (blockIdx.x - 52) * 256 + threadIdx.x;   // 512 blocks * 256 = E_MAX
        int s = ei[e];
        int d = ei[E_MAX + e];
        if (s < N_SURF && d >= N_SURF) {   // w = (~mask_lig[src]) & mask_lig[dst]
            int li = d - N_SURF;
            atomicAdd(&ws[WS_AGG + li * 3 + 0], spos[s * 3 + 0]);
            atomicAdd(&ws[WS_AGG + li * 3 + 1], spos[s * 3 + 1]);
            atomicAdd(&ws[WS_AGG + li * 3 + 2], spos[s * 3 + 2]);
            atomicAdd(&ws[WS_CNT + li], 1.0f);
        }
    }
}

// ---- per-ligand: one BLOCK (256 thr) per node. time MLP + gating + 3-dim fold ----
__global__ __launch_bounds__(256, 4) void k_lig(
    const float* __restrict__ lpos,  const float* __restrict__ tarr,
    const float* __restrict__ Wt1,   const float* __restrict__ bt1,
    const float* __restrict__ Wt2,   const float* __restrict__ bt2,
    const float* __restrict__ Wlig,  const float* __restrict__ blig,
    const float* __restrict__ Wgate, const float* __restrict__ bgate,
    const float* __restrict__ ws,    float* __restrict__ out)
{
    __shared__ float s_emb[64];
    __shared__ float s_h1[256];
    __shared__ float s_ht[64];
    __shared__ float s_red[256];
    __shared__ float s_out[12];
    int t    = threadIdx.x;
    int lane = t & 63;
    int w    = t >> 6;
    int i    = blockIdx.x;

    float tt = tarr[i];
    if (t < 64) {
        const float coef = -0.29710775f;           // -ln(10000)/31
        float ang = tt * expf(coef * (float)(t & 31));
        s_emb[t] = (t < 32) ? sinf(ang) : cosf(ang);
    }
    __syncthreads();
    // h1 = gelu(emb @ Wt1 + bt1): one column per thread, split accumulators
    {
        float acc0 = bt1[t], acc1 = 0.f;
        #pragma unroll 16
        for (int k = 0; k < 64; k += 2) {
            acc0 += s_emb[k]     * Wt1[k * 256 + t];
            acc1 += s_emb[k + 1] * Wt1[(k + 1) * 256 + t];
        }
        float acc = acc0 + acc1;
        s_h1[t] = 0.5f * acc * (1.f + erff(acc * 0.70710678f));
    }
    __syncthreads();
    // ht = h1 @ Wt2 + bt2: 4-way k-split, wave w covers k in [w*64, w*64+64)
    {
        int c0 = w * 64;
        float acc0 = 0.f, acc1 = 0.f;
        #pragma unroll 16
        for (int k = 0; k < 64; k += 2) {
            acc0 += s_h1[c0 + k]     * Wt2[(c0 + k) * 64 + lane];
            acc1 += s_h1[c0 + k + 1] * Wt2[(c0 + k + 1) * 64 + lane];
        }
        s_red[t] = acc0 + acc1;
    }
    __syncthreads();
    if (t < 64) s_ht[t] = bt2[t] + s_red[t] + s_red[t + 64] + s_red[t + 128] + s_red[t + 192];
    __syncthreads();

    float px = lpos[i * 3 + 0], py = lpos[i * 3 + 1], pz = lpos[i * 3 + 2];
    float a0 = 0.f, a1 = 0.f, a2 = 0.f;
    for (int r = 0; r < 2; ++r) {
        int j = r * 256 + t;
        float g0 = bgate[j], g1 = 0.f;
        #pragma unroll 16
        for (int k = 0; k < 64; k += 2) {
            g0 += s_ht[k]     * Wgate[k * 512 + j];
            g1 += s_ht[k + 1] * Wgate[(k + 1) * 512 + j];
        }
        float g  = g0 + g1;
        float p  = blig[j] + px * Wlig[j] + py * Wlig[512 + j] + pz * Wlig[1024 + j];
        float hl = p * (1.f / (1.f + expf(-g)));   // gated term (hbias folded via Whbp)
        a0 += hl * ws[WS_WP + j * 3 + 0];
        a1 += hl * ws[WS_WP + j * 3 + 1];
        a2 += hl * ws[WS_WP + j * 3 + 2];
    }
    // + h_time @ Whbp  (64x3, precomputed)
    if (t < 64) {
        float ht = s_ht[t];
        a0 += ht * ws[WS_WHBP + t * 3 + 0];
        a1 += ht * ws[WS_WHBP + t * 3 + 1];
        a2 += ht * ws[WS_WHBP + t * 3 + 2];
    }
    for (int m = 32; m; m >>= 1) {
        a0 += __shfl_xor(a0, m);
        a1 += __shfl_xor(a1, m);
        a2 += __shfl_xor(a2, m);
    }
    if (lane == 0) { s_out[w * 3 + 0] = a0; s_out[w * 3 + 1] = a1; s_out[w * 3 + 2] = a2; }
    __syncthreads();
    if (t == 0) {
        float b0 = s_out[0] + s_out[3] + s_out[6] + s_out[9];
        float b1 = s_out[1] + s_out[4] + s_out[7] + s_out[10];
        float b2 = s_out[2] + s_out[5] + s_out[8] + s_out[11];
        float d  = ws[WS_CNT + i];
        float s1 = 1.f / sqrtf(1.f + d);
        float s2 = 1.f / (1.f + d);
        float c  = s1 * d;
        float ax = s1 * ws[WS_AGG + i * 3 + 0];
        float ay = s1 * ws[WS_AGG + i * 3 + 1];
        float az = s1 * ws[WS_AGG + i * 3 + 2];
        float acc[3] = {b0, b1, b2};
        #pragma unroll
        for (int jp = 0; jp < 3; ++jp) {
            out[i * 3 + jp] = ax * ws[WS_A3 + 0 + jp] +
                              ay * ws[WS_A3 + 3 + jp] +
                              az * ws[WS_A3 + 6 + jp] +
                              c  * ws[WS_BSP + jp]    +
                              s2 * acc[jp]            +
                              ws[WS_BPOUT + jp];
        }
    }
}

extern "C" void kernel_launch(void* const* d_in, const int* in_sizes, int n_in,
                              void* d_out, int out_size, void* d_ws, size_t ws_size,
                              hipStream_t stream) {
    const float* spos  = (const float*)d_in[0];
    const float* lpos  = (const float*)d_in[1];
    const float* tarr  = (const float*)d_in[2];
    const int*   ei    = (const int*)  d_in[3];
    const float* Wsurf = (const float*)d_in[6];
    const float* bsurf = (const float*)d_in[7];
    const float* Wt1   = (const float*)d_in[8];
    const float* bt1   = (const float*)d_in[9];
    const float* Wt2   = (const float*)d_in[10];
    const float* bt2   = (const float*)d_in[11];
    const float* Wlig  = (const float*)d_in[12];
    const float* blig  = (const float*)d_in[13];
    const float* Wgate = (const float*)d_in[14];
    const float* bgate = (const float*)d_in[15];
    const float* Whb   = (const float*)d_in[16];
    const float* Wgcn  = (const float*)d_in[17];
    const float* bgcn  = (const float*)d_in[18];
    const float* Wpos  = (const float*)d_in[19];
    const float* bpos  = (const float*)d_in[20];
    float* ws  = (float*)d_ws;
    float* out = (float*)d_out;

    hipLaunchKernelGGL(k_prep1, dim3(128), dim3(256), 0, stream, Wgcn, Wpos, ws);
    hipLaunchKernelGGL(k_mid,   dim3(52 + E_MAX / 256), dim3(256), 0, stream,
                       Wsurf, bsurf, bgcn, Wpos, bpos, Whb, ei, spos, ws);
    hipLaunchKernelGGL(k_lig,   dim3(N_LIG), dim3(256), 0, stream,
                       lpos, tarr, Wt1, bt1, Wt2, bt2, Wlig, blig, Wgate, bgate, ws, out);
}